// Round 1
// baseline (734.071 us; speedup 1.0000x reference)
//
#include <hip/hip_runtime.h>

// Problem constants (from reference)
#define NUM_CAMS 6
#define B_DIM    2
#define C_DIM    64
#define H_DIM    232
#define W_DIM    400
#define HW_DIM   (H_DIM * W_DIM)

// One wave (64 lanes) per voxel; lane index = channel.
// - voxel_feats read and out write: fully coalesced (64 lanes x 4B = 256B).
// - mask/grid_y/grid_x/batch_idx: wave-uniform loads (broadcast).
// - image gather: inherently strided by HW between channels (uncoalesced);
//   we issue all 6 camera gathers before consuming any, to overlap latency.
__global__ __launch_bounds__(256) void voxel_fuse_kernel(
    const float* __restrict__ img,   // (6, 2, 64, H, W)
    const float* __restrict__ vox,   // (N, 64)
    const int*   __restrict__ bidx,  // (N,)
    const int*   __restrict__ gy,    // (6, N)
    const int*   __restrict__ gx,    // (6, N)
    const int*   __restrict__ mask,  // (6, N)
    float*       __restrict__ out,   // (N, 64)
    int N)
{
    const int wave = (int)((blockIdx.x * (size_t)blockDim.x + threadIdx.x) >> 6);
    const int c    = threadIdx.x & 63;
    if (wave >= N) return;
    const int n = wave;

    // Wave-uniform metadata loads (issue early).
    int m[NUM_CAMS], y[NUM_CAMS], x[NUM_CAMS];
#pragma unroll
    for (int k = 0; k < NUM_CAMS; ++k) {
        m[k] = mask[(size_t)k * N + n];
        y[k] = gy[(size_t)k * N + n];
        x[k] = gx[(size_t)k * N + n];
    }
    const int b = bidx[n];

    float acc = vox[(size_t)n * C_DIM + c];

    // Base pointer for (b, c) plane; camera k adds k*B*C*HW.
    const float* base = img + ((size_t)b * C_DIM + c) * HW_DIM;

    float v[NUM_CAMS];
#pragma unroll
    for (int k = 0; k < NUM_CAMS; ++k) {
        v[k] = 0.0f;
        if (m[k] > 0) {
            v[k] = base[(size_t)k * (B_DIM * C_DIM * (size_t)HW_DIM)
                        + (size_t)y[k] * W_DIM + (size_t)x[k]];
        }
    }

    acc += ((v[0] + v[1]) + (v[2] + v[3])) + (v[4] + v[5]);
    out[(size_t)n * C_DIM + c] = acc;
}

extern "C" void kernel_launch(void* const* d_in, const int* in_sizes, int n_in,
                              void* d_out, int out_size, void* d_ws, size_t ws_size,
                              hipStream_t stream) {
    const float* img  = (const float*)d_in[0];
    const float* vox  = (const float*)d_in[1];
    const int*   bidx = (const int*)d_in[2];
    const int*   gy   = (const int*)d_in[3];
    const int*   gx   = (const int*)d_in[4];
    const int*   mask = (const int*)d_in[5];
    float* out = (float*)d_out;

    const int N = in_sizes[2];  // voxel_batch_idx has N elements

    const int threads = 256;                 // 4 waves per block
    const int waves_per_block = threads / 64;
    const int blocks = (N + waves_per_block - 1) / waves_per_block;

    voxel_fuse_kernel<<<blocks, threads, 0, stream>>>(img, vox, bidx, gy, gx, mask, out, N);
}

// Round 2
// 151.257 us; speedup vs baseline: 4.8532x; 4.8532x over previous
//
#include <hip/hip_runtime.h>

#define NUM_CAMS 6
#define B_DIM    2
#define C_DIM    64
#define H_DIM    232
#define W_DIM    400
#define HW_DIM   (H_DIM * W_DIM)          // 92800
#define TILES_PER_PLANE (HW_DIM / 64)     // 1450 (exact)
#define PLANES   (NUM_CAMS * B_DIM)       // 12

// ---------------------------------------------------------------------------
// Transpose (k,b,c,h,w) -> (k,b,h,w,c) so a per-point channel gather becomes
// one contiguous 256B read. Classic LDS tile transpose, 64x64 per block.
// Read coalesced along pixels; write coalesced along channels.
// ---------------------------------------------------------------------------
__global__ __launch_bounds__(256) void transpose_kernel(
    const float* __restrict__ img,   // (12, 64, HW)
    float*       __restrict__ wsp)   // (12, HW, 64)
{
    __shared__ float tile[64][65];   // +1 pad: conflict-free both phases

    const int t   = blockIdx.x;      // pixel tile within plane
    const int kb  = blockIdx.y;      // plane index (k*B + b)
    const int px0 = t * 64;
    const size_t plane_in  = (size_t)kb * C_DIM * HW_DIM;
    const size_t plane_out = (size_t)kb * HW_DIM * C_DIM;

    const int tid = threadIdx.x;
    {
        const int px = tid & 63;
        const int c4 = tid >> 6;     // 0..3
#pragma unroll
        for (int r = 0; r < 16; ++r) {
            const int c = c4 * 16 + r;
            tile[c][px] = img[plane_in + (size_t)c * HW_DIM + px0 + px];
        }
    }
    __syncthreads();
    {
        const int c  = tid & 63;
        const int p4 = tid >> 6;     // 0..3
#pragma unroll
        for (int r = 0; r < 16; ++r) {
            const int p = p4 * 16 + r;
            wsp[plane_out + (size_t)(px0 + p) * C_DIM + c] = tile[c][p];
        }
    }
}

// ---------------------------------------------------------------------------
// Fuse: 16 lanes per voxel, float4 per lane (64 channels). Gather per camera
// is one contiguous 256B read from the channel-last image copy.
// ---------------------------------------------------------------------------
__global__ __launch_bounds__(256) void fuse_kernel(
    const float* __restrict__ wsp,   // (12, HW, 64) channel-last
    const float* __restrict__ vox,   // (N, 64)
    const int*   __restrict__ bidx,  // (N,)
    const int*   __restrict__ gy,    // (6, N)
    const int*   __restrict__ gx,    // (6, N)
    const int*   __restrict__ mask,  // (6, N)
    float*       __restrict__ out,   // (N, 64)
    int N)
{
    const size_t gt = blockIdx.x * (size_t)blockDim.x + threadIdx.x;
    const int n = (int)(gt >> 4);
    const int q = (int)(gt & 15);    // which float4 of the 16 per voxel
    if (n >= N) return;

    // Metadata (issue all loads up front).
    int m[NUM_CAMS], y[NUM_CAMS], x[NUM_CAMS];
#pragma unroll
    for (int k = 0; k < NUM_CAMS; ++k) {
        m[k] = mask[(size_t)k * N + n];
        y[k] = gy[(size_t)k * N + n];
        x[k] = gx[(size_t)k * N + n];
    }
    const int b = bidx[n];

    float4 acc = ((const float4*)vox)[(size_t)n * 16 + q];

    const float* base = wsp + (size_t)b * HW_DIM * C_DIM;

    float4 v[NUM_CAMS];
#pragma unroll
    for (int k = 0; k < NUM_CAMS; ++k) {
        v[k] = make_float4(0.f, 0.f, 0.f, 0.f);
        if (m[k] > 0) {
            const float4* p = (const float4*)(base
                + (size_t)k * ((size_t)B_DIM * HW_DIM * C_DIM)
                + ((size_t)y[k] * W_DIM + x[k]) * C_DIM);
            v[k] = p[q];
        }
    }

#pragma unroll
    for (int k = 0; k < NUM_CAMS; ++k) {
        acc.x += v[k].x; acc.y += v[k].y; acc.z += v[k].z; acc.w += v[k].w;
    }

    ((float4*)out)[(size_t)n * 16 + q] = acc;
}

// ---------------------------------------------------------------------------
// Fallback (round-0 kernel): direct gather from original layout, used only if
// the workspace is too small for the transposed copy.
// ---------------------------------------------------------------------------
__global__ __launch_bounds__(256) void fuse_direct_kernel(
    const float* __restrict__ img,
    const float* __restrict__ vox,
    const int*   __restrict__ bidx,
    const int*   __restrict__ gy,
    const int*   __restrict__ gx,
    const int*   __restrict__ mask,
    float*       __restrict__ out,
    int N)
{
    const int wave = (int)((blockIdx.x * (size_t)blockDim.x + threadIdx.x) >> 6);
    const int c    = threadIdx.x & 63;
    if (wave >= N) return;
    const int n = wave;

    int m[NUM_CAMS], y[NUM_CAMS], x[NUM_CAMS];
#pragma unroll
    for (int k = 0; k < NUM_CAMS; ++k) {
        m[k] = mask[(size_t)k * N + n];
        y[k] = gy[(size_t)k * N + n];
        x[k] = gx[(size_t)k * N + n];
    }
    const int b = bidx[n];

    float acc = vox[(size_t)n * C_DIM + c];
    const float* base = img + ((size_t)b * C_DIM + c) * HW_DIM;

    float v[NUM_CAMS];
#pragma unroll
    for (int k = 0; k < NUM_CAMS; ++k) {
        v[k] = 0.0f;
        if (m[k] > 0) {
            v[k] = base[(size_t)k * (B_DIM * C_DIM * (size_t)HW_DIM)
                        + (size_t)y[k] * W_DIM + (size_t)x[k]];
        }
    }
    acc += ((v[0] + v[1]) + (v[2] + v[3])) + (v[4] + v[5]);
    out[(size_t)n * C_DIM + c] = acc;
}

extern "C" void kernel_launch(void* const* d_in, const int* in_sizes, int n_in,
                              void* d_out, int out_size, void* d_ws, size_t ws_size,
                              hipStream_t stream) {
    const float* img  = (const float*)d_in[0];
    const float* vox  = (const float*)d_in[1];
    const int*   bidx = (const int*)d_in[2];
    const int*   gy   = (const int*)d_in[3];
    const int*   gx   = (const int*)d_in[4];
    const int*   mask = (const int*)d_in[5];
    float* out = (float*)d_out;

    const int N = in_sizes[2];

    const size_t img_bytes = (size_t)PLANES * C_DIM * HW_DIM * sizeof(float); // ~285 MB

    if (ws_size >= img_bytes) {
        float* wsp = (float*)d_ws;
        dim3 tgrid(TILES_PER_PLANE, PLANES);
        transpose_kernel<<<tgrid, 256, 0, stream>>>(img, wsp);

        const size_t total_threads = (size_t)N * 16;
        const int blocks = (int)((total_threads + 255) / 256);
        fuse_kernel<<<blocks, 256, 0, stream>>>(wsp, vox, bidx, gy, gx, mask, out, N);
    } else {
        const int waves_per_block = 256 / 64;
        const int blocks = (N + waves_per_block - 1) / waves_per_block;
        fuse_direct_kernel<<<blocks, 256, 0, stream>>>(img, vox, bidx, gy, gx, mask, out, N);
    }
}